// Round 10
// baseline (236.572 us; speedup 1.0000x reference)
//
#include <hip/hip_runtime.h>
#include <hip/hip_bf16.h>
#include <math.h>

// Shapes (fixed by the reference)
#define Bdim 16
#define Ndim 1024
#define Ddim 256
#define Hdim 8
#define HDdim 32
#define INdim 256
#define HIDdim 1024
#define Tdim (Bdim * Ndim)   // 16384 rows

typedef __attribute__((ext_vector_type(8)))  short bf16x8;
typedef __attribute__((ext_vector_type(4)))  short bf16x4;
typedef __attribute__((ext_vector_type(16))) float f32x16;
typedef unsigned int u32;

__device__ inline short f2bf(float x) {
    union { __hip_bfloat16 b; short s; } u;
    u.b = __float2bfloat16(x);
    return u.s;
}

__device__ inline float bf2f(short s) {
    return __uint_as_float(((u32)(unsigned short)s) << 16);
}

// raw v_exp_f32 (scores are bounded; no libm range handling needed)
__device__ inline float fexp2(float x) {
#if __has_builtin(__builtin_amdgcn_exp2f)
    return __builtin_amdgcn_exp2f(x);
#else
    return exp2f(x);
#endif
}

// pack two f32 -> two bf16 in a u32
__device__ inline u32 pack2bf(float a, float b) {
#if __has_builtin(__builtin_amdgcn_cvt_pk_bf16_f32)
    typedef __attribute__((ext_vector_type(2))) __bf16 bf16x2_t;
    union { bf16x2_t v; u32 u; } c;
    c.v = __builtin_amdgcn_cvt_pk_bf16_f32(a, b);
    return c.u;
#else
    u32 ua = __float_as_uint(a), ub = __float_as_uint(b);
    return ((ua + 0x8000u) >> 16) | ((ub + 0x8000u) & 0xffff0000u);
#endif
}

// v_permlane32_swap_b32: after execution a = {a.lo32, b.lo32}, b = {a.hi32, b.hi32}
__device__ inline void plswap(u32 &a, u32 &b) {
    asm volatile("v_permlane32_swap_b32 %0, %1" : "+v"(a), "+v"(b));
}

__device__ inline float gelu_exact(float v) {
    return 0.5f * v * (1.0f + erff(v * 0.70710678118654752f));
}

// ---------------------------------------------------------------------------
// All four weight matrices -> bf16 in ONE dispatch (segment by flat index)
// ---------------------------------------------------------------------------
#define N4_QKV  (3 * INdim * Ddim / 4)   // 49152
#define N4_PROJ (INdim * INdim / 4)      // 16384
#define N4_W1   (HIDdim * Ddim / 4)      // 65536
#define N4_W2   (Ddim * HIDdim / 4)      // 65536

__global__ __launch_bounds__(256) void cvt_all_kernel(const float* __restrict__ s0,
                                                      const float* __restrict__ s1,
                                                      const float* __restrict__ s2,
                                                      const float* __restrict__ s3,
                                                      short* __restrict__ d0,
                                                      short* __restrict__ d1,
                                                      short* __restrict__ d2,
                                                      short* __restrict__ d3) {
    int i = blockIdx.x * 256 + threadIdx.x;
    const float* src; short* dst; int j;
    if (i < N4_QKV)                          { src = s0; dst = d0; j = i; }
    else if (i < N4_QKV + N4_PROJ)           { src = s1; dst = d1; j = i - N4_QKV; }
    else if (i < N4_QKV + N4_PROJ + N4_W1)   { src = s2; dst = d2; j = i - N4_QKV - N4_PROJ; }
    else                                     { src = s3; dst = d3; j = i - N4_QKV - N4_PROJ - N4_W1; }
    float4 v = ((const float4*)src)[j];
    bf16x4 b;
    b[0] = f2bf(v.x); b[1] = f2bf(v.y); b[2] = f2bf(v.z); b[3] = f2bf(v.w);
    ((bf16x4*)dst)[j] = b;
}

// ---------------------------------------------------------------------------
// LayerNorm, wave-per-row (4 rows/block), float4 vectorized.
// ---------------------------------------------------------------------------
__global__ __launch_bounds__(256) void ln4_kernel(const float* __restrict__ x,
                                                  const float* __restrict__ g,
                                                  const float* __restrict__ b,
                                                  float* __restrict__ outf,
                                                  short* __restrict__ outb) {
    int w = threadIdx.x >> 6, lane = threadIdx.x & 63;
    int row = blockIdx.x * 4 + w;
    float4 v = ((const float4*)x)[(size_t)row * 64 + lane];
    float s  = (v.x + v.y) + (v.z + v.w);
    float s2 = (v.x * v.x + v.y * v.y) + (v.z * v.z + v.w * v.w);
    #pragma unroll
    for (int off = 32; off; off >>= 1) {
        s  += __shfl_xor(s,  off, 64);
        s2 += __shfl_xor(s2, off, 64);
    }
    float mu   = s * (1.0f / Ddim);
    float var  = s2 * (1.0f / Ddim) - mu * mu;
    float rstd = rsqrtf(var + 1e-5f);
    float4 gg = ((const float4*)g)[lane];
    float4 bb = ((const float4*)b)[lane];
    float4 r;
    r.x = (v.x - mu) * rstd * gg.x + bb.x;
    r.y = (v.y - mu) * rstd * gg.y + bb.y;
    r.z = (v.z - mu) * rstd * gg.z + bb.z;
    r.w = (v.w - mu) * rstd * gg.w + bb.w;
    if (outf) ((float4*)outf)[(size_t)row * 64 + lane] = r;
    bf16x4 rb;
    rb[0] = f2bf(r.x); rb[1] = f2bf(r.y); rb[2] = f2bf(r.z); rb[3] = f2bf(r.w);
    ((bf16x4*)outb)[(size_t)row * 64 + lane] = rb;
}

// ---------------------------------------------------------------------------
// MFMA GEMM, BM=64, BK=32 (the R3 structure), bijective XCD swizzle.
// COMB=true: fuse attention j-partition combine into A staging (PROJ).
// LNA=true:  fuse LayerNorm into A staging (GELU): per-block prologue
//            computes mu/rstd for its 64 rows (exact ln4 math), then the
//            staging path loads xnew fp32 and applies (v-mu)*rstd*g+b ->
//            bf16 in registers. Kills the LN2 dispatch + h_bf round trip;
//            bf16 values bit-identical to the separate-kernel path.
// ---------------------------------------------------------------------------
#define EPI_NONE 0
#define EPI_PROJ 1
#define EPI_GELU 2
#define EPI_RES  3
#define EPI_QKV  4

#define GPAD32 40   // shorts per LDS row (32 data + 8 pad, 16B-aligned rows)
#define SCALE2Q 0.25505654249892417f   // 32^-0.5 * log2(e)

__device__ inline bf16x8 comb8(bf16x8 a, bf16x8 b, float rl) {
    bf16x8 r;
    #pragma unroll
    for (int i = 0; i < 8; ++i) r[i] = f2bf((bf2f(a[i]) + bf2f(b[i])) * rl);
    return r;
}

template <int EPI, int BN, bool COMB, bool LNA>
__global__ __launch_bounds__(256) void gemm_mfma(const short* __restrict__ A,
                                                 const short* __restrict__ W,
                                                 void* __restrict__ Cv,
                                                 int M, int N, int K,
                                                 const float* __restrict__ bias,
                                                 const float* __restrict__ add1,
                                                 const float* __restrict__ add2,
                                                 const float* __restrict__ lpc,
                                                 const float* __restrict__ xf,
                                                 const float* __restrict__ lng,
                                                 const float* __restrict__ lnb) {
    __shared__ short As[64 * GPAD32];
    __shared__ short Bs[BN * GPAD32];
    __shared__ float mu_s[64], rs_s[64];   // used when LNA
    const int tid = threadIdx.x, w = tid >> 6, lane = tid & 63;
    const int col = lane & 31;
    const int half_id = lane >> 5;

    // bijective XCD swizzle (total grid size is a multiple of 8)
    const int nbx = gridDim.x;
    const int flat = blockIdx.y * nbx + blockIdx.x;
    const int cpx = (nbx * (int)gridDim.y) >> 3;
    const int swz = (flat & 7) * cpx + (flat >> 3);
    const int m0 = (swz / nbx) * 64, n0 = (swz % nbx) * BN;

    // wave tiling: 2 waves along M (32 rows each), 2 along N
    const int wm = (w & 1) * 32;
    const int wn = (BN == 128) ? (w >> 1) * 64 : (w >> 1) * 32;
    constexpr int TN = (BN == 128) ? 2 : 1;

    f32x16 acc[TN];
    #pragma unroll
    for (int t = 0; t < TN; ++t) acc[t] = 0.0f;

    // staging map: A 64x32 = 256 vec8 (1/thread); B BN x 32 (NB/thread)
    const int sra = tid >> 2, ssa = (tid & 3) * 8;
    const int srb = (BN == 128) ? (tid >> 1) : (tid >> 2);
    const int ssb = (BN == 128) ? (tid & 1) * 16 : (tid & 3) * 8;
    constexpr int NB = (BN == 128) ? 2 : 1;

    const short* pAsrc = nullptr;
    const float* pXsrc = nullptr;
    if constexpr (LNA) pXsrc = &xf[(size_t)(m0 + sra) * K + ssa];
    else               pAsrc = &A[(size_t)(m0 + sra) * K + ssa];
    const short* pBsrc = &W[(size_t)(n0 + srb) * K + ssb];
    const float* lpr0 = COMB ? (lpc + (size_t)(m0 + sra) * 8) : nullptr;
    const float* lpr1 = COMB ? (lpr0 + (size_t)Tdim * 8) : nullptr;

    // LNA prologue: each wave computes mu/rstd for its 16 rows (= the rows
    // its threads stage: thread tid stages row tid>>2).
    if constexpr (LNA) {
        #pragma unroll
        for (int rr = 0; rr < 16; ++rr) {
            int row = w * 16 + rr;
            float4 v = ((const float4*)xf)[(size_t)(m0 + row) * 64 + lane];
            float s  = (v.x + v.y) + (v.z + v.w);
            float s2 = (v.x * v.x + v.y * v.y) + (v.z * v.z + v.w * v.w);
            #pragma unroll
            for (int off = 32; off; off >>= 1) {
                s  += __shfl_xor(s,  off, 64);
                s2 += __shfl_xor(s2, off, 64);
            }
            float mu  = s * (1.0f / 256.0f);
            float var = s2 * (1.0f / 256.0f) - mu * mu;
            if (lane == 0) {
                mu_s[row] = mu;
                rs_s[row] = rsqrtf(var + 1e-5f);
            }
        }
        __syncthreads();
    }

    bf16x8 pa, pa2, pb[NB];
    float pl = 0.0f;
    float4 fa0, fa1;

    auto LOAD = [&](int t) {
        if constexpr (LNA) {
            fa0 = *(const float4*)&pXsrc[t * 32];
            fa1 = *(const float4*)&pXsrc[t * 32 + 4];
        } else {
            const short* ap = pAsrc + t * 32;
            pa = *(const bf16x8*)ap;
            if constexpr (COMB) {
                pa2 = *(const bf16x8*)(ap + (size_t)Tdim * 256);
                pl = lpr0[t] + lpr1[t];
            }
        }
        #pragma unroll
        for (int j = 0; j < NB; ++j) pb[j] = *(const bf16x8*)&pBsrc[t * 32 + j * 8];
    };
    auto WRITE = [&](int t) {
        bf16x8 av;
        if constexpr (LNA) {
            float mu = mu_s[sra], rs = rs_s[sra];
            int c0 = t * 32 + ssa;
            float4 g0 = *(const float4*)&lng[c0];
            float4 g1 = *(const float4*)&lng[c0 + 4];
            float4 b0 = *(const float4*)&lnb[c0];
            float4 b1 = *(const float4*)&lnb[c0 + 4];
            av[0] = f2bf((fa0.x - mu) * rs * g0.x + b0.x);
            av[1] = f2bf((fa0.y - mu) * rs * g0.y + b0.y);
            av[2] = f2bf((fa0.z - mu) * rs * g0.z + b0.z);
            av[3] = f2bf((fa0.w - mu) * rs * g0.w + b0.w);
            av[4] = f2bf((fa1.x - mu) * rs * g1.x + b1.x);
            av[5] = f2bf((fa1.y - mu) * rs * g1.y + b1.y);
            av[6] = f2bf((fa1.z - mu) * rs * g1.z + b1.z);
            av[7] = f2bf((fa1.w - mu) * rs * g1.w + b1.w);
        } else if constexpr (COMB) {
            av = comb8(pa, pa2, 1.0f / pl);
        } else {
            av = pa;
        }
        *(bf16x8*)&As[sra * GPAD32 + ssa] = av;
        #pragma unroll
        for (int j = 0; j < NB; ++j) *(bf16x8*)&Bs[srb * GPAD32 + ssb + j * 8] = pb[j];
    };

    const int T = K >> 5;
    LOAD(0);
    for (int kt = 0; kt < T; ++kt) {
        __syncthreads();
        WRITE(kt);
        __syncthreads();

        if (kt + 1 < T) LOAD(kt + 1);

        #pragma unroll
        for (int ks = 0; ks < 2; ++ks) {
            bf16x8 af = *(const bf16x8*)&As[(wm + col) * GPAD32 + ks * 16 + half_id * 8];
            bf16x8 bfv[TN];
            #pragma unroll
            for (int t = 0; t < TN; ++t)
                bfv[t] = *(const bf16x8*)&Bs[(wn + t * 32 + col) * GPAD32 + ks * 16 + half_id * 8];
            #pragma unroll
            for (int t = 0; t < TN; ++t)
                acc[t] = __builtin_amdgcn_mfma_f32_32x32x16_bf16(af, bfv[t], acc[t], 0, 0, 0);
        }
    }

    float* Cf = (float*)Cv;
    short* Cb = (short*)Cv;
    #pragma unroll
    for (int r = 0; r < 16; ++r) {
        int row = m0 + wm + (r & 3) + 8 * (r >> 2) + 4 * half_id;
        #pragma unroll
        for (int t = 0; t < TN; ++t) {
            int cn = n0 + wn + t * 32 + col;
            size_t off = (size_t)row * N + cn;
            float v = acc[t][r];
            if (EPI != EPI_NONE && EPI != EPI_QKV) v += bias[cn];
            if (EPI == EPI_QKV && cn < 256) v *= SCALE2Q;
            if (EPI == EPI_GELU) v = gelu_exact(v);
            if (EPI == EPI_PROJ) v += add1[off] + add2[off];
            if (EPI == EPI_RES)  v += add1[off];
            if (EPI == EPI_PROJ || EPI == EPI_RES) Cf[off] = v;
            else                                   Cb[off] = f2bf(v);
        }
    }
}

// ---------------------------------------------------------------------------
// One-time V transpose: qkv[b][n][512+head*32+d] -> vT[(bh*32+d)][n].
// ---------------------------------------------------------------------------
#define VTPAD 136

__global__ __launch_bounds__(256) void vtrans_kernel(const short* __restrict__ qkv,
                                                     short* __restrict__ vT) {
    __shared__ short Tl[32 * VTPAD];
    const int tid = threadIdx.x;
    const int bh = blockIdx.x, c = blockIdx.y;
    const int b = bh >> 3, head = bh & 7;
    {
        int r = tid >> 1, hv = tid & 1;
        const short* src = qkv + (size_t)b * Ndim * 768 + (size_t)(c * 128 + r) * 768
                           + 512 + head * 32 + hv * 16;
        bf16x8 v0 = *(const bf16x8*)&src[0];
        bf16x8 v1 = *(const bf16x8*)&src[8];
        #pragma unroll
        for (int i = 0; i < 8; ++i) {
            Tl[(hv * 16 + i) * VTPAD + r]     = v0[i];
            Tl[(hv * 16 + 8 + i) * VTPAD + r] = v1[i];
        }
    }
    __syncthreads();
    {
        int d = tid >> 3, j16 = (tid & 7) * 16;
        short* dst = vT + (size_t)(bh * 32 + d) * Ndim + c * 128 + j16;
        *(bf16x8*)&dst[0] = *(const bf16x8*)&Tl[d * VTPAD + j16];
        *(bf16x8*)&dst[8] = *(const bf16x8*)&Tl[d * VTPAD + j16 + 8];
    }
}

// ---------------------------------------------------------------------------
// MFMA attention, j-split flash (maxless -> partials additive). Partials bf16.
// In-register P relayout (cvt_pk + permlane32_swap), T14 async staging,
// jt software pipeline, 1D grid with XCD-locality decode (all 16 WGs of a
// (b,h) on one XCD so its 128KB K/V stays in that XCD's L2).
// ---------------------------------------------------------------------------
#define KVPAD 40
#define CHUNK 128

__global__ __launch_bounds__(256) void attn_mfma_kernel(const short* __restrict__ qkv,
                                                        const short* __restrict__ vT,
                                                        short* __restrict__ opart,
                                                        float* __restrict__ lpart) {
    __shared__ short Ks[CHUNK * KVPAD];
    __shared__ short Vt[32 * VTPAD];

    const int tid = threadIdx.x;
    const int w = tid >> 6;
    const int lane = tid & 63;
    const int col = lane & 31;
    const int half_id = lane >> 5;

    const int id = blockIdx.x;            // 0..2047
    const int xcd = id & 7;
    const int s_ = id >> 3;               // 0..255
    const int bh = ((s_ >> 4) << 3) | xcd; // 16 bh per XCD
    const int qp = s_ & 15;
    const int qblk = qp & 7;
    const int part = qp >> 3;

    const int b = bh >> 3, head = bh & 7;
    const int q0w = qblk * 128 + w * 32;

    const size_t qkvb = (size_t)b * Ndim * 768;
    short* op = opart + (size_t)part * Tdim * 256;
    float* lp = lpart + (size_t)part * Tdim * 8;

    const int sr = tid >> 1, shv = tid & 1;
    const short* ksrc = qkv + qkvb + (size_t)sr * 768 + 256 + head * 32 + shv * 16;
    const int sd = tid >> 3, sj16 = (tid & 7) * 16;
    const short* vsrc = vT + (size_t)(bh * 32 + sd) * Ndim + sj16;

    bf16x8 qf[2];
    {
        const short* qrow = qkv + qkvb + (size_t)(q0w + col) * 768 + head * 32;
        #pragma unroll
        for (int kh = 0; kh < 2; ++kh)
            qf[kh] = *(const bf16x8*)&qrow[kh * 16 + half_id * 8];
    }

    bf16x8 vone;
    #pragma unroll
    for (int i = 0; i < 8; ++i) vone[i] = (short)0x3F80;   // bf16 1.0

    f32x16 o_acc = 0.0f, l_acc = 0.0f;

    const int c0 = part * 4;

    bf16x8 rk0, rk1, rv0, rv1;
    {
        const short* kp = ksrc + (size_t)(c0 * CHUNK) * 768;
        rk0 = *(const bf16x8*)&kp[0];
        rk1 = *(const bf16x8*)&kp[8];
        const short* vp = vsrc + c0 * CHUNK;
        rv0 = *(const bf16x8*)&vp[0];
        rv1 = *(const bf16x8*)&vp[8];
    }

    #pragma unroll
    for (int ci = 0; ci < 4; ++ci) {
        if (ci != 0) __syncthreads();
        *(bf16x8*)&Ks[sr * KVPAD + shv * 16]     = rk0;
        *(bf16x8*)&Ks[sr * KVPAD + shv * 16 + 8] = rk1;
        *(bf16x8*)&Vt[sd * VTPAD + sj16]     = rv0;
        *(bf16x8*)&Vt[sd * VTPAD + sj16 + 8] = rv1;
        __syncthreads();

        if (ci < 3) {
            const short* kp = ksrc + (size_t)((c0 + ci + 1) * CHUNK) * 768;
            rk0 = *(const bf16x8*)&kp[0];
            rk1 = *(const bf16x8*)&kp[8];
            const short* vp = vsrc + (c0 + ci + 1) * CHUNK;
            rv0 = *(const bf16x8*)&vp[0];
            rv1 = *(const bf16x8*)&vp[8];
        }

        f32x16 s_cur;
        {
            bf16x8 kf0 = *(bf16x8*)&Ks[col * KVPAD + half_id * 8];
            bf16x8 kf1 = *(bf16x8*)&Ks[col * KVPAD + 16 + half_id * 8];
            f32x16 z = 0.0f;
            z = __builtin_amdgcn_mfma_f32_32x32x16_bf16(kf0, qf[0], z, 0, 0, 0);
            z = __builtin_amdgcn_mfma_f32_32x32x16_bf16(kf1, qf[1], z, 0, 0, 0);
            s_cur = z;
        }
        #pragma unroll
        for (int jt = 0; jt < 4; ++jt) {
            f32x16 s_next;
            if (jt < 3) {
                bf16x8 kf0 = *(bf16x8*)&Ks[((jt + 1) * 32 + col) * KVPAD + half_id * 8];
                bf16x8 kf1 = *(bf16x8*)&Ks[((jt + 1) * 32 + col) * KVPAD + 16 + half_id * 8];
                f32x16 z = 0.0f;
                z = __builtin_amdgcn_mfma_f32_32x32x16_bf16(kf0, qf[0], z, 0, 0, 0);
                z = __builtin_amdgcn_mfma_f32_32x32x16_bf16(kf1, qf[1], z, 0, 0, 0);
                s_next = z;
            }

            bf16x8 vf0 = *(bf16x8*)&Vt[col * VTPAD + jt * 32 + half_id * 8];
            bf16x8 vf1 = *(bf16x8*)&Vt[col * VTPAD + jt * 32 + 16 + half_id * 8];

            u32 wd[8];
            #pragma unroll
            for (int g = 0; g < 8; ++g) {
                float e0 = fexp2(s_cur[2 * g + 0]);
                float e1 = fexp2(s_cur[2 * g + 1]);
                wd[g] = pack2bf(e0, e1);
            }
            plswap(wd[0], wd[2]); plswap(wd[1], wd[3]);
            plswap(wd[4], wd[6]); plswap(wd[5], wd[7]);

            union { u32 u[4]; bf16x8 v; } p0, p1;
            p0.u[0] = wd[0]; p0.u[1] = wd[1]; p0.u[2] = wd[2]; p0.u[3] = wd[3];
            p1.u[0] = wd[4]; p1.u[1] = wd[5]; p1.u[2] = wd[6]; p1.u[3] = wd[7];

            __builtin_amdgcn_s_setprio(1);
            o_acc = __builtin_amdgcn_mfma_f32_32x32x16_bf16(p0.v, vf0, o_acc, 0, 0, 0);
            o_acc = __builtin_amdgcn_mfma_f32_32x32x16_bf16(p1.v, vf1, o_acc, 0, 0, 0);
            l_acc = __builtin_amdgcn_mfma_f32_32x32x16_bf16(p0.v, vone, l_acc, 0, 0, 0);
            l_acc = __builtin_amdgcn_mfma_f32_32x32x16_bf16(p1.v, vone, l_acc, 0, 0, 0);
            __builtin_amdgcn_s_setprio(0);

            if (jt < 3) s_cur = s_next;
        }
    }

    #pragma unroll
    for (int r = 0; r < 16; ++r) {
        int q_r = (r & 3) + 8 * (r >> 2) + 4 * half_id;
        size_t gq = (size_t)(b * Ndim + q0w + q_r);
        op[gq * INdim + head * 32 + col] = f2bf(o_acc[r]);
    }
    if (col < 16) {
        int r = col;
        int q_r = (r & 3) + 8 * (r >> 2) + 4 * half_id;
        lp[(size_t)(b * Ndim + q0w + q_r) * 8 + head] = l_acc[r];
    }
}

// ---------------------------------------------------------------------------
// launch
// ---------------------------------------------------------------------------
extern "C" void kernel_launch(void* const* d_in, const int* in_sizes, int n_in,
                              void* d_out, int out_size, void* d_ws, size_t ws_size,
                              hipStream_t stream) {
    const float* x     = (const float*)d_in[0];
    const float* g1    = (const float*)d_in[2];
    const float* b1    = (const float*)d_in[3];
    const float* Wqkv  = (const float*)d_in[4];
    const float* Wproj = (const float*)d_in[5];
    const float* bproj = (const float*)d_in[6];
    const float* g2    = (const float*)d_in[7];
    const float* b2    = (const float*)d_in[8];
    const float* W1    = (const float*)d_in[9];
    const float* bb1   = (const float*)d_in[10];
    const float* W2    = (const float*)d_in[11];
    const float* bb2   = (const float*)d_in[12];
    float* out = (float*)d_out;

    // workspace:
    //  [0,16M)  h fp32
    //  [16,24M) h_bf
    //  [24,48M) qkv_bf (dead after attn) -> xnew fp32 [24,40M)
    //  [48,64M) opart bf16 x2 (dead after PROJ) -> mid_bf [48,80M)
    //  [80,81M) lpart fp32 [2][Tdim*8]
    //  [81,89M) vT bf16
    //  [89,91M) weights bf16
    char* ws = (char*)d_ws;
    float* h      = (float*)(ws);
    short* h_bf   = (short*)(ws + (size_t)(16u << 20));
    short* qkv_bf = (short*)(ws + (size_t)(24u << 20));
    float* xnew   = (float*)(ws + (size_t)(24u << 20));
    short* opart  = (short*)(ws + (size_t)(48u << 20));
    short* mid_bf = (short*)(ws + (size_t)(48u << 20));
    float* lpart  = (float*)(ws + (size_t)(80u << 20));
    short* vT     = (short*)(ws + (size_t)(81u << 20));
    short* wqkv_b = (short*)(ws + (size_t)(89u << 20));
    short* wproj_b= (short*)(ws + (size_t)(89u << 20) + 768 * 1024);
    short* w1_b   = (short*)(ws + (size_t)(90u << 20));
    short* w2_b   = (short*)(ws + (size_t)(90u << 20) + 512 * 1024);

    // 0) all weights -> bf16 (single dispatch)
    cvt_all_kernel<<<(N4_QKV + N4_PROJ + N4_W1 + N4_W2 + 255) / 256, 256, 0, stream>>>(
        Wqkv, Wproj, W1, W2, wqkv_b, wproj_b, w1_b, w2_b);

    // 1) LN1: x -> h (fp32) + h_bf
    ln4_kernel<<<Tdim / 4, 256, 0, stream>>>(x, g1, b1, h, h_bf);
    // 2) qkv_bf = h_bf @ Wqkv^T, q columns pre-scaled by 32^-0.5*log2e
    gemm_mfma<EPI_QKV, 128, false, false><<<dim3(768 / 128, Tdim / 64), 256, 0, stream>>>(
        h_bf, wqkv_b, qkv_bf, Tdim, 768, 256, nullptr, nullptr, nullptr, nullptr,
        nullptr, nullptr, nullptr);
    // 2b) V transpose (once)
    vtrans_kernel<<<dim3(Bdim * Hdim, Ndim / 128), 256, 0, stream>>>(qkv_bf, vT);
    // 3) attention partials (j-split x2), XCD-locality 1D grid
    attn_mfma_kernel<<<2048, 256, 0, stream>>>(qkv_bf, vT, opart, lpart);
    // 4) xnew = ((O0+O1)/l) @ Wproj^T + bproj + h + x   (combine fused into A-staging)
    gemm_mfma<EPI_PROJ, 64, true, false><<<dim3(256 / 64, Tdim / 64), 256, 0, stream>>>(
        opart, wproj_b, xnew, Tdim, 256, 256, bproj, h, x, lpart,
        nullptr, nullptr, nullptr);
    // 5) mid_bf = gelu(LN2(xnew) @ W1^T + bb1)   (LN2 fused into A-staging)
    gemm_mfma<EPI_GELU, 128, false, true><<<dim3(1024 / 128, Tdim / 64), 256, 0, stream>>>(
        nullptr, w1_b, mid_bf, Tdim, 1024, 256, bb1, nullptr, nullptr, nullptr,
        xnew, g2, b2);
    // 6) out = xnew + mid @ W2^T + bb2
    gemm_mfma<EPI_RES, 64, false, false><<<dim3(256 / 64, Tdim / 64), 256, 0, stream>>>(
        mid_bf, w2_b, out, Tdim, 256, 1024, bb2, xnew, nullptr, nullptr,
        nullptr, nullptr, nullptr);
}

// Round 11
// 216.933 us; speedup vs baseline: 1.0905x; 1.0905x over previous
//
#include <hip/hip_runtime.h>
#include <hip/hip_bf16.h>
#include <math.h>

// Shapes (fixed by the reference)
#define Bdim 16
#define Ndim 1024
#define Ddim 256
#define Hdim 8
#define HDdim 32
#define INdim 256
#define HIDdim 1024
#define Tdim (Bdim * Ndim)   // 16384 rows

typedef __attribute__((ext_vector_type(8)))  short bf16x8;
typedef __attribute__((ext_vector_type(4)))  short bf16x4;
typedef __attribute__((ext_vector_type(16))) float f32x16;
typedef unsigned int u32;

__device__ inline short f2bf(float x) {
    union { __hip_bfloat16 b; short s; } u;
    u.b = __float2bfloat16(x);
    return u.s;
}

__device__ inline float bf2f(short s) {
    return __uint_as_float(((u32)(unsigned short)s) << 16);
}

// raw v_exp_f32 (scores are bounded; no libm range handling needed)
__device__ inline float fexp2(float x) {
#if __has_builtin(__builtin_amdgcn_exp2f)
    return __builtin_amdgcn_exp2f(x);
#else
    return exp2f(x);
#endif
}

// pack two f32 -> two bf16 in a u32
__device__ inline u32 pack2bf(float a, float b) {
#if __has_builtin(__builtin_amdgcn_cvt_pk_bf16_f32)
    typedef __attribute__((ext_vector_type(2))) __bf16 bf16x2_t;
    union { bf16x2_t v; u32 u; } c;
    c.v = __builtin_amdgcn_cvt_pk_bf16_f32(a, b);
    return c.u;
#else
    u32 ua = __float_as_uint(a), ub = __float_as_uint(b);
    return ((ua + 0x8000u) >> 16) | ((ub + 0x8000u) & 0xffff0000u);
#endif
}

// v_permlane32_swap_b32: after execution a = {a.lo32, b.lo32}, b = {a.hi32, b.hi32}
__device__ inline void plswap(u32 &a, u32 &b) {
    asm volatile("v_permlane32_swap_b32 %0, %1" : "+v"(a), "+v"(b));
}

__device__ inline float gelu_exact(float v) {
    return 0.5f * v * (1.0f + erff(v * 0.70710678118654752f));
}

// direct global->LDS copy, 16B per lane. LDS dest is wave-uniform base +
// lane*16 (HW-enforced); global src is per-lane.
typedef __attribute__((address_space(1))) const u32 gas_t;
typedef __attribute__((address_space(3))) u32 las_t;
__device__ inline void gl16(const short* g, short* l) {
    __builtin_amdgcn_global_load_lds((gas_t*)g, (las_t*)l, 16, 0, 0);
}

// ---------------------------------------------------------------------------
// All four weight matrices -> bf16 in ONE dispatch (segment by flat index)
// ---------------------------------------------------------------------------
#define N4_QKV  (3 * INdim * Ddim / 4)   // 49152
#define N4_PROJ (INdim * INdim / 4)      // 16384
#define N4_W1   (HIDdim * Ddim / 4)      // 65536
#define N4_W2   (Ddim * HIDdim / 4)      // 65536

__global__ __launch_bounds__(256) void cvt_all_kernel(const float* __restrict__ s0,
                                                      const float* __restrict__ s1,
                                                      const float* __restrict__ s2,
                                                      const float* __restrict__ s3,
                                                      short* __restrict__ d0,
                                                      short* __restrict__ d1,
                                                      short* __restrict__ d2,
                                                      short* __restrict__ d3) {
    int i = blockIdx.x * 256 + threadIdx.x;
    const float* src; short* dst; int j;
    if (i < N4_QKV)                          { src = s0; dst = d0; j = i; }
    else if (i < N4_QKV + N4_PROJ)           { src = s1; dst = d1; j = i - N4_QKV; }
    else if (i < N4_QKV + N4_PROJ + N4_W1)   { src = s2; dst = d2; j = i - N4_QKV - N4_PROJ; }
    else                                     { src = s3; dst = d3; j = i - N4_QKV - N4_PROJ - N4_W1; }
    float4 v = ((const float4*)src)[j];
    bf16x4 b;
    b[0] = f2bf(v.x); b[1] = f2bf(v.y); b[2] = f2bf(v.z); b[3] = f2bf(v.w);
    ((bf16x4*)dst)[j] = b;
}

// ---------------------------------------------------------------------------
// LayerNorm, wave-per-row (4 rows/block), float4 vectorized.
// ---------------------------------------------------------------------------
__global__ __launch_bounds__(256) void ln4_kernel(const float* __restrict__ x,
                                                  const float* __restrict__ g,
                                                  const float* __restrict__ b,
                                                  float* __restrict__ outf,
                                                  short* __restrict__ outb) {
    int w = threadIdx.x >> 6, lane = threadIdx.x & 63;
    int row = blockIdx.x * 4 + w;
    float4 v = ((const float4*)x)[(size_t)row * 64 + lane];
    float s  = (v.x + v.y) + (v.z + v.w);
    float s2 = (v.x * v.x + v.y * v.y) + (v.z * v.z + v.w * v.w);
    #pragma unroll
    for (int off = 32; off; off >>= 1) {
        s  += __shfl_xor(s,  off, 64);
        s2 += __shfl_xor(s2, off, 64);
    }
    float mu   = s * (1.0f / Ddim);
    float var  = s2 * (1.0f / Ddim) - mu * mu;
    float rstd = rsqrtf(var + 1e-5f);
    float4 gg = ((const float4*)g)[lane];
    float4 bb = ((const float4*)b)[lane];
    float4 r;
    r.x = (v.x - mu) * rstd * gg.x + bb.x;
    r.y = (v.y - mu) * rstd * gg.y + bb.y;
    r.z = (v.z - mu) * rstd * gg.z + bb.z;
    r.w = (v.w - mu) * rstd * gg.w + bb.w;
    if (outf) ((float4*)outf)[(size_t)row * 64 + lane] = r;
    bf16x4 rb;
    rb[0] = f2bf(r.x); rb[1] = f2bf(r.y); rb[2] = f2bf(r.z); rb[3] = f2bf(r.w);
    ((bf16x4*)outb)[(size_t)row * 64 + lane] = rb;
}

// ---------------------------------------------------------------------------
// MFMA GEMM, BM=64, BK=32, bijective XCD swizzle.
// GL=true (QKV/GELU/RES): direct-to-LDS staging via global_load_lds width=16,
//   linear double-buffered LDS, both-sides XOR chunk swizzle
//   (store chunk (l&3)^((l>>3)&3); read chunk c^((row>>1)&3) -> ~4-way),
//   single vmcnt(0)+barrier per BK step (T3-minimal).
// GL=false (PROJ): old reg-staged path, padded LDS, 2 barriers; COMB fuses
//   the attention j-partition combine into A staging (kt == head index).
// ---------------------------------------------------------------------------
#define EPI_NONE 0
#define EPI_PROJ 1
#define EPI_GELU 2
#define EPI_RES  3
#define EPI_QKV  4

#define GPAD32 40   // shorts per LDS row for GL=false (32 data + 8 pad)
#define SCALE2Q 0.25505654249892417f   // 32^-0.5 * log2(e)

__device__ inline bf16x8 comb8(bf16x8 a, bf16x8 b, float rl) {
    bf16x8 r;
    #pragma unroll
    for (int i = 0; i < 8; ++i) r[i] = f2bf((bf2f(a[i]) + bf2f(b[i])) * rl);
    return r;
}

template <int EPI, int BN, bool COMB, bool GL>
__global__ __launch_bounds__(256) void gemm_mfma(const short* __restrict__ A,
                                                 const short* __restrict__ W,
                                                 void* __restrict__ Cv,
                                                 int M, int N, int K,
                                                 const float* __restrict__ bias,
                                                 const float* __restrict__ add1,
                                                 const float* __restrict__ add2,
                                                 const float* __restrict__ lpc) {
    constexpr int AP = GL ? 32 : GPAD32;
    constexpr int NB2 = GL ? 2 : 1;
    __shared__ short As[NB2][64 * AP];
    __shared__ short Bs[NB2][BN * AP];
    const int tid = threadIdx.x, w = tid >> 6, lane = tid & 63;
    const int col = lane & 31;
    const int half_id = lane >> 5;

    // bijective XCD swizzle (total grid size is a multiple of 8)
    const int nbx = gridDim.x;
    const int flat = blockIdx.y * nbx + blockIdx.x;
    const int cpx = (nbx * (int)gridDim.y) >> 3;
    const int swz = (flat & 7) * cpx + (flat >> 3);
    const int m0 = (swz / nbx) * 64, n0 = (swz % nbx) * BN;

    // wave tiling: 2 waves along M (32 rows each), 2 along N
    const int wm = (w & 1) * 32;
    const int wn = (BN == 128) ? (w >> 1) * 64 : (w >> 1) * 32;
    constexpr int TN = (BN == 128) ? 2 : 1;

    f32x16 acc[TN];
    #pragma unroll
    for (int t = 0; t < TN; ++t) acc[t] = 0.0f;

    const int T = K >> 5;

    if constexpr (GL) {
        // per-lane global sources (chunk-swizzled); LDS dests wave-uniform
        const int srow = lane >> 2;                       // 0..15
        const int schk = (lane & 3) ^ ((lane >> 3) & 3);  // inverse of read swz
        const short* gA = &A[(size_t)(m0 + w * 16 + srow) * K + schk * 8];
        const short* gB0;
        const short* gB1 = nullptr;
        if constexpr (BN == 128) {
            gB0 = &W[(size_t)(n0 + w * 32 + srow) * K + schk * 8];
            gB1 = &W[(size_t)(n0 + w * 32 + 16 + srow) * K + schk * 8];
        } else {
            gB0 = &W[(size_t)(n0 + w * 16 + srow) * K + schk * 8];
        }

        auto STAGE = [&](int buf, int kt) {
            gl16(gA + kt * 32, &As[buf][w * 512]);
            if constexpr (BN == 128) {
                gl16(gB0 + kt * 32, &Bs[buf][w * 1024]);
                gl16(gB1 + kt * 32, &Bs[buf][w * 1024 + 512]);
            } else {
                gl16(gB0 + kt * 32, &Bs[buf][w * 512]);
            }
        };

        STAGE(0, 0);
        asm volatile("s_waitcnt vmcnt(0)" ::: "memory");
        __builtin_amdgcn_s_barrier();

        int cur = 0;
        for (int kt = 0; kt < T; ++kt) {
            if (kt + 1 < T) STAGE(cur ^ 1, kt + 1);
            #pragma unroll
            for (int ks = 0; ks < 2; ++ks) {
                const int c = ks * 2 + half_id;
                const int Ra = wm + col;
                bf16x8 af = *(const bf16x8*)&As[cur][Ra * 32 + (c ^ ((Ra >> 1) & 3)) * 8];
                bf16x8 bfv[TN];
                #pragma unroll
                for (int t = 0; t < TN; ++t) {
                    const int Rb = wn + t * 32 + col;
                    bfv[t] = *(const bf16x8*)&Bs[cur][Rb * 32 + (c ^ ((Rb >> 1) & 3)) * 8];
                }
                #pragma unroll
                for (int t = 0; t < TN; ++t)
                    acc[t] = __builtin_amdgcn_mfma_f32_32x32x16_bf16(af, bfv[t], acc[t], 0, 0, 0);
            }
            asm volatile("s_waitcnt vmcnt(0)" ::: "memory");
            __builtin_amdgcn_s_barrier();
            cur ^= 1;
        }
    } else {
        // reg-staged path (PROJ/COMB)
        const int sra = tid >> 2, ssa = (tid & 3) * 8;
        const int srb = (BN == 128) ? (tid >> 1) : (tid >> 2);
        const int ssb = (BN == 128) ? (tid & 1) * 16 : (tid & 3) * 8;
        constexpr int NB = (BN == 128) ? 2 : 1;

        const short* pAsrc = &A[(size_t)(m0 + sra) * K + ssa];
        const short* pBsrc = &W[(size_t)(n0 + srb) * K + ssb];
        const float* lpr0 = COMB ? (lpc + (size_t)(m0 + sra) * 8) : nullptr;
        const float* lpr1 = COMB ? (lpr0 + (size_t)Tdim * 8) : nullptr;

        bf16x8 pa, pa2, pb[NB];
        float pl = 0.0f;
        pa = *(const bf16x8*)&pAsrc[0];
        if constexpr (COMB) {
            pa2 = *(const bf16x8*)(pAsrc + (size_t)Tdim * 256);
            pl = lpr0[0] + lpr1[0];
        }
        #pragma unroll
        for (int j = 0; j < NB; ++j) pb[j] = *(const bf16x8*)&pBsrc[j * 8];

        for (int kt = 0; kt < T; ++kt) {
            __syncthreads();
            {
                bf16x8 av = pa;
                if constexpr (COMB) av = comb8(pa, pa2, 1.0f / pl);
                *(bf16x8*)&As[0][sra * GPAD32 + ssa] = av;
            }
            #pragma unroll
            for (int j = 0; j < NB; ++j) *(bf16x8*)&Bs[0][srb * GPAD32 + ssb + j * 8] = pb[j];
            __syncthreads();

            if (kt + 1 < T) {
                const short* a = pAsrc + (kt + 1) * 32;
                const short* b = pBsrc + (kt + 1) * 32;
                pa = *(const bf16x8*)&a[0];
                if constexpr (COMB) {
                    pa2 = *(const bf16x8*)(a + (size_t)Tdim * 256);
                    pl = lpr0[kt + 1] + lpr1[kt + 1];
                }
                #pragma unroll
                for (int j = 0; j < NB; ++j) pb[j] = *(const bf16x8*)&b[j * 8];
            }

            #pragma unroll
            for (int ks = 0; ks < 2; ++ks) {
                bf16x8 af = *(const bf16x8*)&As[0][(wm + col) * GPAD32 + ks * 16 + half_id * 8];
                bf16x8 bfv[TN];
                #pragma unroll
                for (int t = 0; t < TN; ++t)
                    bfv[t] = *(const bf16x8*)&Bs[0][(wn + t * 32 + col) * GPAD32 + ks * 16 + half_id * 8];
                #pragma unroll
                for (int t = 0; t < TN; ++t)
                    acc[t] = __builtin_amdgcn_mfma_f32_32x32x16_bf16(af, bfv[t], acc[t], 0, 0, 0);
            }
        }
    }

    float* Cf = (float*)Cv;
    short* Cb = (short*)Cv;
    #pragma unroll
    for (int r = 0; r < 16; ++r) {
        int row = m0 + wm + (r & 3) + 8 * (r >> 2) + 4 * half_id;
        #pragma unroll
        for (int t = 0; t < TN; ++t) {
            int cn = n0 + wn + t * 32 + col;
            size_t off = (size_t)row * N + cn;
            float v = acc[t][r];
            if (EPI != EPI_NONE && EPI != EPI_QKV) v += bias[cn];
            if (EPI == EPI_QKV && cn < 256) v *= SCALE2Q;
            if (EPI == EPI_GELU) v = gelu_exact(v);
            if (EPI == EPI_PROJ) v += add1[off] + add2[off];
            if (EPI == EPI_RES)  v += add1[off];
            if (EPI == EPI_PROJ || EPI == EPI_RES) Cf[off] = v;
            else                                   Cb[off] = f2bf(v);
        }
    }
}

// ---------------------------------------------------------------------------
// One-time V transpose: qkv[b][n][512+head*32+d] -> vT[(bh*32+d)][n].
// ---------------------------------------------------------------------------
#define VTPAD 136

__global__ __launch_bounds__(256) void vtrans_kernel(const short* __restrict__ qkv,
                                                     short* __restrict__ vT) {
    __shared__ short Tl[32 * VTPAD];
    const int tid = threadIdx.x;
    const int bh = blockIdx.x, c = blockIdx.y;
    const int b = bh >> 3, head = bh & 7;
    {
        int r = tid >> 1, hv = tid & 1;
        const short* src = qkv + (size_t)b * Ndim * 768 + (size_t)(c * 128 + r) * 768
                           + 512 + head * 32 + hv * 16;
        bf16x8 v0 = *(const bf16x8*)&src[0];
        bf16x8 v1 = *(const bf16x8*)&src[8];
        #pragma unroll
        for (int i = 0; i < 8; ++i) {
            Tl[(hv * 16 + i) * VTPAD + r]     = v0[i];
            Tl[(hv * 16 + 8 + i) * VTPAD + r] = v1[i];
        }
    }
    __syncthreads();
    {
        int d = tid >> 3, j16 = (tid & 7) * 16;
        short* dst = vT + (size_t)(bh * 32 + d) * Ndim + c * 128 + j16;
        *(bf16x8*)&dst[0] = *(const bf16x8*)&Tl[d * VTPAD + j16];
        *(bf16x8*)&dst[8] = *(const bf16x8*)&Tl[d * VTPAD + j16 + 8];
    }
}

// ---------------------------------------------------------------------------
// MFMA attention, j-split flash (maxless -> partials additive). Partials bf16.
// In-register P relayout (cvt_pk + permlane32_swap), T14 async staging,
// jt software pipeline, 1D grid with XCD-locality decode (all 16 WGs of a
// (b,h) on one XCD so its 128KB K/V stays in that XCD's L2).
// ---------------------------------------------------------------------------
#define KVPAD 40
#define CHUNK 128

__global__ __launch_bounds__(256) void attn_mfma_kernel(const short* __restrict__ qkv,
                                                        const short* __restrict__ vT,
                                                        short* __restrict__ opart,
                                                        float* __restrict__ lpart) {
    __shared__ short Ks[CHUNK * KVPAD];
    __shared__ short Vt[32 * VTPAD];

    const int tid = threadIdx.x;
    const int w = tid >> 6;
    const int lane = tid & 63;
    const int col = lane & 31;
    const int half_id = lane >> 5;

    const int id = blockIdx.x;            // 0..2047
    const int xcd = id & 7;
    const int s_ = id >> 3;               // 0..255
    const int bh = ((s_ >> 4) << 3) | xcd; // 16 bh per XCD
    const int qp = s_ & 15;
    const int qblk = qp & 7;
    const int part = qp >> 3;

    const int b = bh >> 3, head = bh & 7;
    const int q0w = qblk * 128 + w * 32;

    const size_t qkvb = (size_t)b * Ndim * 768;
    short* op = opart + (size_t)part * Tdim * 256;
    float* lp = lpart + (size_t)part * Tdim * 8;

    const int sr = tid >> 1, shv = tid & 1;
    const short* ksrc = qkv + qkvb + (size_t)sr * 768 + 256 + head * 32 + shv * 16;
    const int sd = tid >> 3, sj16 = (tid & 7) * 16;
    const short* vsrc = vT + (size_t)(bh * 32 + sd) * Ndim + sj16;

    bf16x8 qf[2];
    {
        const short* qrow = qkv + qkvb + (size_t)(q0w + col) * 768 + head * 32;
        #pragma unroll
        for (int kh = 0; kh < 2; ++kh)
            qf[kh] = *(const bf16x8*)&qrow[kh * 16 + half_id * 8];
    }

    bf16x8 vone;
    #pragma unroll
    for (int i = 0; i < 8; ++i) vone[i] = (short)0x3F80;   // bf16 1.0

    f32x16 o_acc = 0.0f, l_acc = 0.0f;

    const int c0 = part * 4;

    bf16x8 rk0, rk1, rv0, rv1;
    {
        const short* kp = ksrc + (size_t)(c0 * CHUNK) * 768;
        rk0 = *(const bf16x8*)&kp[0];
        rk1 = *(const bf16x8*)&kp[8];
        const short* vp = vsrc + c0 * CHUNK;
        rv0 = *(const bf16x8*)&vp[0];
        rv1 = *(const bf16x8*)&vp[8];
    }

    #pragma unroll
    for (int ci = 0; ci < 4; ++ci) {
        if (ci != 0) __syncthreads();
        *(bf16x8*)&Ks[sr * KVPAD + shv * 16]     = rk0;
        *(bf16x8*)&Ks[sr * KVPAD + shv * 16 + 8] = rk1;
        *(bf16x8*)&Vt[sd * VTPAD + sj16]     = rv0;
        *(bf16x8*)&Vt[sd * VTPAD + sj16 + 8] = rv1;
        __syncthreads();

        if (ci < 3) {
            const short* kp = ksrc + (size_t)((c0 + ci + 1) * CHUNK) * 768;
            rk0 = *(const bf16x8*)&kp[0];
            rk1 = *(const bf16x8*)&kp[8];
            const short* vp = vsrc + (c0 + ci + 1) * CHUNK;
            rv0 = *(const bf16x8*)&vp[0];
            rv1 = *(const bf16x8*)&vp[8];
        }

        f32x16 s_cur;
        {
            bf16x8 kf0 = *(bf16x8*)&Ks[col * KVPAD + half_id * 8];
            bf16x8 kf1 = *(bf16x8*)&Ks[col * KVPAD + 16 + half_id * 8];
            f32x16 z = 0.0f;
            z = __builtin_amdgcn_mfma_f32_32x32x16_bf16(kf0, qf[0], z, 0, 0, 0);
            z = __builtin_amdgcn_mfma_f32_32x32x16_bf16(kf1, qf[1], z, 0, 0, 0);
            s_cur = z;
        }
        #pragma unroll
        for (int jt = 0; jt < 4; ++jt) {
            f32x16 s_next;
            if (jt < 3) {
                bf16x8 kf0 = *(bf16x8*)&Ks[((jt + 1) * 32 + col) * KVPAD + half_id * 8];
                bf16x8 kf1 = *(bf16x8*)&Ks[((jt + 1) * 32 + col) * KVPAD + 16 + half_id * 8];
                f32x16 z = 0.0f;
                z = __builtin_amdgcn_mfma_f32_32x32x16_bf16(kf0, qf[0], z, 0, 0, 0);
                z = __builtin_amdgcn_mfma_f32_32x32x16_bf16(kf1, qf[1], z, 0, 0, 0);
                s_next = z;
            }

            bf16x8 vf0 = *(bf16x8*)&Vt[col * VTPAD + jt * 32 + half_id * 8];
            bf16x8 vf1 = *(bf16x8*)&Vt[col * VTPAD + jt * 32 + 16 + half_id * 8];

            u32 wd[8];
            #pragma unroll
            for (int g = 0; g < 8; ++g) {
                float e0 = fexp2(s_cur[2 * g + 0]);
                float e1 = fexp2(s_cur[2 * g + 1]);
                wd[g] = pack2bf(e0, e1);
            }
            plswap(wd[0], wd[2]); plswap(wd[1], wd[3]);
            plswap(wd[4], wd[6]); plswap(wd[5], wd[7]);

            union { u32 u[4]; bf16x8 v; } p0, p1;
            p0.u[0] = wd[0]; p0.u[1] = wd[1]; p0.u[2] = wd[2]; p0.u[3] = wd[3];
            p1.u[0] = wd[4]; p1.u[1] = wd[5]; p1.u[2] = wd[6]; p1.u[3] = wd[7];

            __builtin_amdgcn_s_setprio(1);
            o_acc = __builtin_amdgcn_mfma_f32_32x32x16_bf16(p0.v, vf0, o_acc, 0, 0, 0);
            o_acc = __builtin_amdgcn_mfma_f32_32x32x16_bf16(p1.v, vf1, o_acc, 0, 0, 0);
            l_acc = __builtin_amdgcn_mfma_f32_32x32x16_bf16(p0.v, vone, l_acc, 0, 0, 0);
            l_acc = __builtin_amdgcn_mfma_f32_32x32x16_bf16(p1.v, vone, l_acc, 0, 0, 0);
            __builtin_amdgcn_s_setprio(0);

            if (jt < 3) s_cur = s_next;
        }
    }

    #pragma unroll
    for (int r = 0; r < 16; ++r) {
        int q_r = (r & 3) + 8 * (r >> 2) + 4 * half_id;
        size_t gq = (size_t)(b * Ndim + q0w + q_r);
        op[gq * INdim + head * 32 + col] = f2bf(o_acc[r]);
    }
    if (col < 16) {
        int r = col;
        int q_r = (r & 3) + 8 * (r >> 2) + 4 * half_id;
        lp[(size_t)(b * Ndim + q0w + q_r) * 8 + head] = l_acc[r];
    }
}

// ---------------------------------------------------------------------------
// launch
// ---------------------------------------------------------------------------
extern "C" void kernel_launch(void* const* d_in, const int* in_sizes, int n_in,
                              void* d_out, int out_size, void* d_ws, size_t ws_size,
                              hipStream_t stream) {
    const float* x     = (const float*)d_in[0];
    const float* g1    = (const float*)d_in[2];
    const float* b1    = (const float*)d_in[3];
    const float* Wqkv  = (const float*)d_in[4];
    const float* Wproj = (const float*)d_in[5];
    const float* bproj = (const float*)d_in[6];
    const float* g2    = (const float*)d_in[7];
    const float* b2    = (const float*)d_in[8];
    const float* W1    = (const float*)d_in[9];
    const float* bb1   = (const float*)d_in[10];
    const float* W2    = (const float*)d_in[11];
    const float* bb2   = (const float*)d_in[12];
    float* out = (float*)d_out;

    // workspace:
    //  [0,16M)  h fp32
    //  [16,24M) h_bf
    //  [24,48M) qkv_bf (dead after attn) -> xnew fp32 [24,40M)
    //  [48,64M) opart bf16 x2 (dead after PROJ) -> mid_bf [48,80M)
    //  [80,81M) lpart fp32 [2][Tdim*8]
    //  [81,89M) vT bf16
    //  [89,91M) weights bf16
    char* ws = (char*)d_ws;
    float* h      = (float*)(ws);
    short* h_bf   = (short*)(ws + (size_t)(16u << 20));
    short* qkv_bf = (short*)(ws + (size_t)(24u << 20));
    float* xnew   = (float*)(ws + (size_t)(24u << 20));
    short* opart  = (short*)(ws + (size_t)(48u << 20));
    short* mid_bf = (short*)(ws + (size_t)(48u << 20));
    float* lpart  = (float*)(ws + (size_t)(80u << 20));
    short* vT     = (short*)(ws + (size_t)(81u << 20));
    short* wqkv_b = (short*)(ws + (size_t)(89u << 20));
    short* wproj_b= (short*)(ws + (size_t)(89u << 20) + 768 * 1024);
    short* w1_b   = (short*)(ws + (size_t)(90u << 20));
    short* w2_b   = (short*)(ws + (size_t)(90u << 20) + 512 * 1024);

    // 0) all weights -> bf16 (single dispatch)
    cvt_all_kernel<<<(N4_QKV + N4_PROJ + N4_W1 + N4_W2 + 255) / 256, 256, 0, stream>>>(
        Wqkv, Wproj, W1, W2, wqkv_b, wproj_b, w1_b, w2_b);

    // 1) LN1: x -> h (fp32) + h_bf
    ln4_kernel<<<Tdim / 4, 256, 0, stream>>>(x, g1, b1, h, h_bf);
    // 2) qkv_bf = h_bf @ Wqkv^T, q columns pre-scaled by 32^-0.5*log2e
    gemm_mfma<EPI_QKV, 128, false, true><<<dim3(768 / 128, Tdim / 64), 256, 0, stream>>>(
        h_bf, wqkv_b, qkv_bf, Tdim, 768, 256, nullptr, nullptr, nullptr, nullptr);
    // 2b) V transpose (once)
    vtrans_kernel<<<dim3(Bdim * Hdim, Ndim / 128), 256, 0, stream>>>(qkv_bf, vT);
    // 3) attention partials (j-split x2), XCD-locality 1D grid
    attn_mfma_kernel<<<2048, 256, 0, stream>>>(qkv_bf, vT, opart, lpart);
    // 4) xnew = ((O0+O1)/l) @ Wproj^T + bproj + h + x   (combine fused, reg-staged)
    gemm_mfma<EPI_PROJ, 64, true, false><<<dim3(256 / 64, Tdim / 64), 256, 0, stream>>>(
        opart, wproj_b, xnew, Tdim, 256, 256, bproj, h, x, lpart);
    // 5) LN2: xnew -> h_bf
    ln4_kernel<<<Tdim / 4, 256, 0, stream>>>(xnew, g2, b2, nullptr, h_bf);
    // 6) mid_bf = gelu(h2 @ W1^T + bb1)
    gemm_mfma<EPI_GELU, 128, false, true><<<dim3(1024 / 128, Tdim / 64), 256, 0, stream>>>(
        h_bf, w1_b, mid_bf, Tdim, 1024, 256, bb1, nullptr, nullptr, nullptr);
    // 7) out = xnew + mid @ W2^T + bb2
    gemm_mfma<EPI_RES, 64, false, true><<<dim3(256 / 64, Tdim / 64), 256, 0, stream>>>(
        mid_bf, w2_b, out, Tdim, 256, 1024, bb2, xnew, nullptr, nullptr);
}

// Round 12
// 211.220 us; speedup vs baseline: 1.1200x; 1.0271x over previous
//
#include <hip/hip_runtime.h>
#include <hip/hip_bf16.h>
#include <math.h>

// Shapes (fixed by the reference)
#define Bdim 16
#define Ndim 1024
#define Ddim 256
#define Hdim 8
#define HDdim 32
#define INdim 256
#define HIDdim 1024
#define Tdim (Bdim * Ndim)   // 16384 rows

typedef __attribute__((ext_vector_type(8)))  short bf16x8;
typedef __attribute__((ext_vector_type(4)))  short bf16x4;
typedef __attribute__((ext_vector_type(16))) float f32x16;
typedef unsigned int u32;

__device__ inline short f2bf(float x) {
    union { __hip_bfloat16 b; short s; } u;
    u.b = __float2bfloat16(x);
    return u.s;
}

__device__ inline float bf2f(short s) {
    return __uint_as_float(((u32)(unsigned short)s) << 16);
}

// raw v_exp_f32 (scores are bounded; no libm range handling needed)
__device__ inline float fexp2(float x) {
#if __has_builtin(__builtin_amdgcn_exp2f)
    return __builtin_amdgcn_exp2f(x);
#else
    return exp2f(x);
#endif
}

// pack two f32 -> two bf16 in a u32
__device__ inline u32 pack2bf(float a, float b) {
#if __has_builtin(__builtin_amdgcn_cvt_pk_bf16_f32)
    typedef __attribute__((ext_vector_type(2))) __bf16 bf16x2_t;
    union { bf16x2_t v; u32 u; } c;
    c.v = __builtin_amdgcn_cvt_pk_bf16_f32(a, b);
    return c.u;
#else
    u32 ua = __float_as_uint(a), ub = __float_as_uint(b);
    return ((ua + 0x8000u) >> 16) | ((ub + 0x8000u) & 0xffff0000u);
#endif
}

// v_permlane32_swap_b32: after execution a = {a.lo32, b.lo32}, b = {a.hi32, b.hi32}
__device__ inline void plswap(u32 &a, u32 &b) {
    asm volatile("v_permlane32_swap_b32 %0, %1" : "+v"(a), "+v"(b));
}

__device__ inline float gelu_exact(float v) {
    return 0.5f * v * (1.0f + erff(v * 0.70710678118654752f));
}

// direct global->LDS copy, 16B per lane. LDS dest is wave-uniform base +
// lane*16 (HW-enforced); global src is per-lane.
typedef __attribute__((address_space(1))) const u32 gas_t;
typedef __attribute__((address_space(3))) u32 las_t;
__device__ inline void gl16(const short* g, short* l) {
    __builtin_amdgcn_global_load_lds((gas_t*)g, (las_t*)l, 16, 0, 0);
}

// ---------------------------------------------------------------------------
// All four weight matrices -> bf16 in ONE dispatch (segment by flat index)
// ---------------------------------------------------------------------------
#define N4_QKV  (3 * INdim * Ddim / 4)   // 49152
#define N4_PROJ (INdim * INdim / 4)      // 16384
#define N4_W1   (HIDdim * Ddim / 4)      // 65536
#define N4_W2   (Ddim * HIDdim / 4)      // 65536

__global__ __launch_bounds__(256) void cvt_all_kernel(const float* __restrict__ s0,
                                                      const float* __restrict__ s1,
                                                      const float* __restrict__ s2,
                                                      const float* __restrict__ s3,
                                                      short* __restrict__ d0,
                                                      short* __restrict__ d1,
                                                      short* __restrict__ d2,
                                                      short* __restrict__ d3) {
    int i = blockIdx.x * 256 + threadIdx.x;
    const float* src; short* dst; int j;
    if (i < N4_QKV)                          { src = s0; dst = d0; j = i; }
    else if (i < N4_QKV + N4_PROJ)           { src = s1; dst = d1; j = i - N4_QKV; }
    else if (i < N4_QKV + N4_PROJ + N4_W1)   { src = s2; dst = d2; j = i - N4_QKV - N4_PROJ; }
    else                                     { src = s3; dst = d3; j = i - N4_QKV - N4_PROJ - N4_W1; }
    float4 v = ((const float4*)src)[j];
    bf16x4 b;
    b[0] = f2bf(v.x); b[1] = f2bf(v.y); b[2] = f2bf(v.z); b[3] = f2bf(v.w);
    ((bf16x4*)dst)[j] = b;
}

// ---------------------------------------------------------------------------
// LayerNorm, wave-per-row (4 rows/block), float4 vectorized.
// ---------------------------------------------------------------------------
__global__ __launch_bounds__(256) void ln4_kernel(const float* __restrict__ x,
                                                  const float* __restrict__ g,
                                                  const float* __restrict__ b,
                                                  float* __restrict__ outf,
                                                  short* __restrict__ outb) {
    int w = threadIdx.x >> 6, lane = threadIdx.x & 63;
    int row = blockIdx.x * 4 + w;
    float4 v = ((const float4*)x)[(size_t)row * 64 + lane];
    float s  = (v.x + v.y) + (v.z + v.w);
    float s2 = (v.x * v.x + v.y * v.y) + (v.z * v.z + v.w * v.w);
    #pragma unroll
    for (int off = 32; off; off >>= 1) {
        s  += __shfl_xor(s,  off, 64);
        s2 += __shfl_xor(s2, off, 64);
    }
    float mu   = s * (1.0f / Ddim);
    float var  = s2 * (1.0f / Ddim) - mu * mu;
    float rstd = rsqrtf(var + 1e-5f);
    float4 gg = ((const float4*)g)[lane];
    float4 bb = ((const float4*)b)[lane];
    float4 r;
    r.x = (v.x - mu) * rstd * gg.x + bb.x;
    r.y = (v.y - mu) * rstd * gg.y + bb.y;
    r.z = (v.z - mu) * rstd * gg.z + bb.z;
    r.w = (v.w - mu) * rstd * gg.w + bb.w;
    if (outf) ((float4*)outf)[(size_t)row * 64 + lane] = r;
    bf16x4 rb;
    rb[0] = f2bf(r.x); rb[1] = f2bf(r.y); rb[2] = f2bf(r.z); rb[3] = f2bf(r.w);
    ((bf16x4*)outb)[(size_t)row * 64 + lane] = rb;
}

// ---------------------------------------------------------------------------
// m97-template GEMM: 128x128 tile, BK=64, global_load_lds width=16 staging,
// single-buffered LDS, 2 barriers per BK step. Read-chunk XOR swizzle
// c^(row&7) with inverse-swizzled per-lane global source (both-sides rule).
// Used for QKV (N=768) and GELU (N=1024): grids 768/1024 blocks = 3-4/CU.
// ---------------------------------------------------------------------------
#define EPI_NONE 0
#define EPI_PROJ 1
#define EPI_GELU 2
#define EPI_RES  3
#define EPI_QKV  4

#define SCALE2Q 0.25505654249892417f   // 32^-0.5 * log2(e)

template <int EPI>
__global__ __launch_bounds__(256) void gemm128(const short* __restrict__ A,
                                               const short* __restrict__ W,
                                               short* __restrict__ C,
                                               int N, int K,
                                               const float* __restrict__ bias) {
    __shared__ __attribute__((aligned(16))) short As[128 * 64];
    __shared__ __attribute__((aligned(16))) short Bs[128 * 64];
    const int tid = threadIdx.x, w = tid >> 6, lane = tid & 63;
    const int col = lane & 31;
    const int half_id = lane >> 5;

    // bijective XCD swizzle (total grid size is a multiple of 8)
    const int nbx = gridDim.x;
    const int flat = blockIdx.y * nbx + blockIdx.x;
    const int cpx = (nbx * (int)gridDim.y) >> 3;
    const int swz = (flat & 7) * cpx + (flat >> 3);
    const int m0 = (swz / nbx) * 128, n0 = (swz % nbx) * 128;

    // wave tiling: 2x2 waves, each owns 64x64 (2x2 of 32x32)
    const int wm = (w & 1) * 64;
    const int wn = (w >> 1) * 64;

    f32x16 acc[2][2];
    #pragma unroll
    for (int i = 0; i < 2; ++i) { acc[i][0] = 0.0f; acc[i][1] = 0.0f; }

    // staging: wave w stages A rows w*32..+31 and B rows w*32..+31, BK=64.
    // one gl16 covers 8 rows (64 lanes x 16B = 8 x 128B rows); 4 per matrix.
    // lane l -> row sub = l>>3, source chunk = (l&7) ^ ((l>>3)&7) (inverse of
    // the read swizzle so LDS[row][c] holds global chunk c ^ (row&7)).
    const int lrow = lane >> 3;
    const int lchk = (lane & 7) ^ lrow;
    const short* gA = &A[(size_t)(m0 + w * 32 + lrow) * K + lchk * 8];
    const short* gB = &W[(size_t)(n0 + w * 32 + lrow) * K + lchk * 8];
    short* lA = &As[(w * 32) * 64];
    short* lB = &Bs[(w * 32) * 64];

    const int T = K >> 6;
    for (int kt = 0; kt < T; ++kt) {
        if (kt) __syncthreads();            // prev compute done reading LDS
        #pragma unroll
        for (int i = 0; i < 4; ++i) {
            gl16(gA + (size_t)(i * 8) * K + kt * 64, lA + i * 512);
            gl16(gB + (size_t)(i * 8) * K + kt * 64, lB + i * 512);
        }
        __syncthreads();                    // stage visible (vmcnt drained)

        #pragma unroll
        for (int ks = 0; ks < 4; ++ks) {
            const int c = ks * 2 + half_id;   // global chunk 0..7
            bf16x8 af[2], bfv[2];
            #pragma unroll
            for (int t = 0; t < 2; ++t) {
                const int Ra = wm + t * 32 + col;
                af[t] = *(const bf16x8*)&As[Ra * 64 + ((c ^ (Ra & 7)) * 8)];
                const int Rb = wn + t * 32 + col;
                bfv[t] = *(const bf16x8*)&Bs[Rb * 64 + ((c ^ (Rb & 7)) * 8)];
            }
            #pragma unroll
            for (int tm = 0; tm < 2; ++tm)
                #pragma unroll
                for (int tn = 0; tn < 2; ++tn)
                    acc[tm][tn] = __builtin_amdgcn_mfma_f32_32x32x16_bf16(
                        af[tm], bfv[tn], acc[tm][tn], 0, 0, 0);
        }
    }

    #pragma unroll
    for (int tm = 0; tm < 2; ++tm) {
        #pragma unroll
        for (int r = 0; r < 16; ++r) {
            int row = m0 + wm + tm * 32 + (r & 3) + 8 * (r >> 2) + 4 * half_id;
            #pragma unroll
            for (int tn = 0; tn < 2; ++tn) {
                int cn = n0 + wn + tn * 32 + col;
                float v = acc[tm][tn][r];
                if (EPI == EPI_QKV && cn < 256) v *= SCALE2Q;
                if (EPI == EPI_GELU) v = gelu_exact(v + bias[cn]);
                C[(size_t)row * N + cn] = f2bf(v);
            }
        }
    }
}

// ---------------------------------------------------------------------------
// Reg-staged GEMM, BM=64, BK=32 (R9-measured config) for PROJ and RES.
// COMB=true fuses the attention j-partition combine into A staging (PROJ;
// valid because BK=32 == head dim, so kt IS the head index).
// ---------------------------------------------------------------------------
#define GPAD32 40   // shorts per LDS row (32 data + 8 pad, 16B-aligned rows)

__device__ inline bf16x8 comb8(bf16x8 a, bf16x8 b, float rl) {
    bf16x8 r;
    #pragma unroll
    for (int i = 0; i < 8; ++i) r[i] = f2bf((bf2f(a[i]) + bf2f(b[i])) * rl);
    return r;
}

template <int EPI, int BN, bool COMB>
__global__ __launch_bounds__(256) void gemm_mfma(const short* __restrict__ A,
                                                 const short* __restrict__ W,
                                                 void* __restrict__ Cv,
                                                 int M, int N, int K,
                                                 const float* __restrict__ bias,
                                                 const float* __restrict__ add1,
                                                 const float* __restrict__ add2,
                                                 const float* __restrict__ lpc) {
    __shared__ short As[64 * GPAD32];
    __shared__ short Bs[BN * GPAD32];
    const int tid = threadIdx.x, w = tid >> 6, lane = tid & 63;
    const int col = lane & 31;
    const int half_id = lane >> 5;

    // bijective XCD swizzle (total grid size is a multiple of 8)
    const int nbx = gridDim.x;
    const int flat = blockIdx.y * nbx + blockIdx.x;
    const int cpx = (nbx * (int)gridDim.y) >> 3;
    const int swz = (flat & 7) * cpx + (flat >> 3);
    const int m0 = (swz / nbx) * 64, n0 = (swz % nbx) * BN;

    const int wm = (w & 1) * 32;
    const int wn = (BN == 128) ? (w >> 1) * 64 : (w >> 1) * 32;
    constexpr int TN = (BN == 128) ? 2 : 1;

    f32x16 acc[TN];
    #pragma unroll
    for (int t = 0; t < TN; ++t) acc[t] = 0.0f;

    const int sra = tid >> 2, ssa = (tid & 3) * 8;
    const int srb = (BN == 128) ? (tid >> 1) : (tid >> 2);
    const int ssb = (BN == 128) ? (tid & 1) * 16 : (tid & 3) * 8;
    constexpr int NB = (BN == 128) ? 2 : 1;

    const short* pAsrc = &A[(size_t)(m0 + sra) * K + ssa];
    const short* pBsrc = &W[(size_t)(n0 + srb) * K + ssb];
    const float* lpr0 = COMB ? (lpc + (size_t)(m0 + sra) * 8) : nullptr;
    const float* lpr1 = COMB ? (lpr0 + (size_t)Tdim * 8) : nullptr;

    bf16x8 pa, pa2, pb[NB];
    float pl = 0.0f;
    pa = *(const bf16x8*)&pAsrc[0];
    if constexpr (COMB) {
        pa2 = *(const bf16x8*)(pAsrc + (size_t)Tdim * 256);
        pl = lpr0[0] + lpr1[0];
    }
    #pragma unroll
    for (int j = 0; j < NB; ++j) pb[j] = *(const bf16x8*)&pBsrc[j * 8];

    const int T = K >> 5;
    for (int kt = 0; kt < T; ++kt) {
        __syncthreads();
        {
            bf16x8 av = pa;
            if constexpr (COMB) av = comb8(pa, pa2, 1.0f / pl);
            *(bf16x8*)&As[sra * GPAD32 + ssa] = av;
        }
        #pragma unroll
        for (int j = 0; j < NB; ++j) *(bf16x8*)&Bs[srb * GPAD32 + ssb + j * 8] = pb[j];
        __syncthreads();

        if (kt + 1 < T) {
            const short* a = pAsrc + (kt + 1) * 32;
            const short* b = pBsrc + (kt + 1) * 32;
            pa = *(const bf16x8*)&a[0];
            if constexpr (COMB) {
                pa2 = *(const bf16x8*)(a + (size_t)Tdim * 256);
                pl = lpr0[kt + 1] + lpr1[kt + 1];
            }
            #pragma unroll
            for (int j = 0; j < NB; ++j) pb[j] = *(const bf16x8*)&b[j * 8];
        }

        #pragma unroll
        for (int ks = 0; ks < 2; ++ks) {
            bf16x8 af = *(const bf16x8*)&As[(wm + col) * GPAD32 + ks * 16 + half_id * 8];
            bf16x8 bfv[TN];
            #pragma unroll
            for (int t = 0; t < TN; ++t)
                bfv[t] = *(const bf16x8*)&Bs[(wn + t * 32 + col) * GPAD32 + ks * 16 + half_id * 8];
            #pragma unroll
            for (int t = 0; t < TN; ++t)
                acc[t] = __builtin_amdgcn_mfma_f32_32x32x16_bf16(af, bfv[t], acc[t], 0, 0, 0);
        }
    }

    float* Cf = (float*)Cv;
    short* Cb = (short*)Cv;
    #pragma unroll
    for (int r = 0; r < 16; ++r) {
        int row = m0 + wm + (r & 3) + 8 * (r >> 2) + 4 * half_id;
        #pragma unroll
        for (int t = 0; t < TN; ++t) {
            int cn = n0 + wn + t * 32 + col;
            size_t off = (size_t)row * N + cn;
            float v = acc[t][r];
            if (EPI != EPI_NONE && EPI != EPI_QKV) v += bias[cn];
            if (EPI == EPI_GELU) v = gelu_exact(v);
            if (EPI == EPI_PROJ) v += add1[off] + add2[off];
            if (EPI == EPI_RES)  v += add1[off];
            if (EPI == EPI_PROJ || EPI == EPI_RES) Cf[off] = v;
            else                                   Cb[off] = f2bf(v);
        }
    }
}

// ---------------------------------------------------------------------------
// One-time V transpose: qkv[b][n][512+head*32+d] -> vT[(bh*32+d)][n].
// ---------------------------------------------------------------------------
#define VTPAD 136

__global__ __launch_bounds__(256) void vtrans_kernel(const short* __restrict__ qkv,
                                                     short* __restrict__ vT) {
    __shared__ short Tl[32 * VTPAD];
    const int tid = threadIdx.x;
    const int bh = blockIdx.x, c = blockIdx.y;
    const int b = bh >> 3, head = bh & 7;
    {
        int r = tid >> 1, hv = tid & 1;
        const short* src = qkv + (size_t)b * Ndim * 768 + (size_t)(c * 128 + r) * 768
                           + 512 + head * 32 + hv * 16;
        bf16x8 v0 = *(const bf16x8*)&src[0];
        bf16x8 v1 = *(const bf16x8*)&src[8];
        #pragma unroll
        for (int i = 0; i < 8; ++i) {
            Tl[(hv * 16 + i) * VTPAD + r]     = v0[i];
            Tl[(hv * 16 + 8 + i) * VTPAD + r] = v1[i];
        }
    }
    __syncthreads();
    {
        int d = tid >> 3, j16 = (tid & 7) * 16;
        short* dst = vT + (size_t)(bh * 32 + d) * Ndim + c * 128 + j16;
        *(bf16x8*)&dst[0] = *(const bf16x8*)&Tl[d * VTPAD + j16];
        *(bf16x8*)&dst[8] = *(const bf16x8*)&Tl[d * VTPAD + j16 + 8];
    }
}

// ---------------------------------------------------------------------------
// MFMA attention, j-split flash (maxless -> partials additive). Partials bf16.
// In-register P relayout (cvt_pk + permlane32_swap), T14 async staging,
// jt software pipeline, 1D grid with XCD-locality decode (all 16 WGs of a
// (b,h) on one XCD so its 128KB K/V stays in that XCD's L2).
// ---------------------------------------------------------------------------
#define KVPAD 40
#define CHUNK 128

__global__ __launch_bounds__(256) void attn_mfma_kernel(const short* __restrict__ qkv,
                                                        const short* __restrict__ vT,
                                                        short* __restrict__ opart,
                                                        float* __restrict__ lpart) {
    __shared__ short Ks[CHUNK * KVPAD];
    __shared__ short Vt[32 * VTPAD];

    const int tid = threadIdx.x;
    const int w = tid >> 6;
    const int lane = tid & 63;
    const int col = lane & 31;
    const int half_id = lane >> 5;

    const int id = blockIdx.x;            // 0..2047
    const int xcd = id & 7;
    const int s_ = id >> 3;               // 0..255
    const int bh = ((s_ >> 4) << 3) | xcd; // 16 bh per XCD
    const int qp = s_ & 15;
    const int qblk = qp & 7;
    const int part = qp >> 3;

    const int b = bh >> 3, head = bh & 7;
    const int q0w = qblk * 128 + w * 32;

    const size_t qkvb = (size_t)b * Ndim * 768;
    short* op = opart + (size_t)part * Tdim * 256;
    float* lp = lpart + (size_t)part * Tdim * 8;

    const int sr = tid >> 1, shv = tid & 1;
    const short* ksrc = qkv + qkvb + (size_t)sr * 768 + 256 + head * 32 + shv * 16;
    const int sd = tid >> 3, sj16 = (tid & 7) * 16;
    const short* vsrc = vT + (size_t)(bh * 32 + sd) * Ndim + sj16;

    bf16x8 qf[2];
    {
        const short* qrow = qkv + qkvb + (size_t)(q0w + col) * 768 + head * 32;
        #pragma unroll
        for (int kh = 0; kh < 2; ++kh)
            qf[kh] = *(const bf16x8*)&qrow[kh * 16 + half_id * 8];
    }

    bf16x8 vone;
    #pragma unroll
    for (int i = 0; i < 8; ++i) vone[i] = (short)0x3F80;   // bf16 1.0

    f32x16 o_acc = 0.0f, l_acc = 0.0f;

    const int c0 = part * 4;

    bf16x8 rk0, rk1, rv0, rv1;
    {
        const short* kp = ksrc + (size_t)(c0 * CHUNK) * 768;
        rk0 = *(const bf16x8*)&kp[0];
        rk1 = *(const bf16x8*)&kp[8];
        const short* vp = vsrc + c0 * CHUNK;
        rv0 = *(const bf16x8*)&vp[0];
        rv1 = *(const bf16x8*)&vp[8];
    }

    #pragma unroll
    for (int ci = 0; ci < 4; ++ci) {
        if (ci != 0) __syncthreads();
        *(bf16x8*)&Ks[sr * KVPAD + shv * 16]     = rk0;
        *(bf16x8*)&Ks[sr * KVPAD + shv * 16 + 8] = rk1;
        *(bf16x8*)&Vt[sd * VTPAD + sj16]     = rv0;
        *(bf16x8*)&Vt[sd * VTPAD + sj16 + 8] = rv1;
        __syncthreads();

        if (ci < 3) {
            const short* kp = ksrc + (size_t)((c0 + ci + 1) * CHUNK) * 768;
            rk0 = *(const bf16x8*)&kp[0];
            rk1 = *(const bf16x8*)&kp[8];
            const short* vp = vsrc + (c0 + ci + 1) * CHUNK;
            rv0 = *(const bf16x8*)&vp[0];
            rv1 = *(const bf16x8*)&vp[8];
        }

        f32x16 s_cur;
        {
            bf16x8 kf0 = *(bf16x8*)&Ks[col * KVPAD + half_id * 8];
            bf16x8 kf1 = *(bf16x8*)&Ks[col * KVPAD + 16 + half_id * 8];
            f32x16 z = 0.0f;
            z = __builtin_amdgcn_mfma_f32_32x32x16_bf16(kf0, qf[0], z, 0, 0, 0);
            z = __builtin_amdgcn_mfma_f32_32x32x16_bf16(kf1, qf[1], z, 0, 0, 0);
            s_cur = z;
        }
        #pragma unroll
        for (int jt = 0; jt < 4; ++jt) {
            f32x16 s_next;
            if (jt < 3) {
                bf16x8 kf0 = *(bf16x8*)&Ks[((jt + 1) * 32 + col) * KVPAD + half_id * 8];
                bf16x8 kf1 = *(bf16x8*)&Ks[((jt + 1) * 32 + col) * KVPAD + 16 + half_id * 8];
                f32x16 z = 0.0f;
                z = __builtin_amdgcn_mfma_f32_32x32x16_bf16(kf0, qf[0], z, 0, 0, 0);
                z = __builtin_amdgcn_mfma_f32_32x32x16_bf16(kf1, qf[1], z, 0, 0, 0);
                s_next = z;
            }

            bf16x8 vf0 = *(bf16x8*)&Vt[col * VTPAD + jt * 32 + half_id * 8];
            bf16x8 vf1 = *(bf16x8*)&Vt[col * VTPAD + jt * 32 + 16 + half_id * 8];

            u32 wd[8];
            #pragma unroll
            for (int g = 0; g < 8; ++g) {
                float e0 = fexp2(s_cur[2 * g + 0]);
                float e1 = fexp2(s_cur[2 * g + 1]);
                wd[g] = pack2bf(e0, e1);
            }
            plswap(wd[0], wd[2]); plswap(wd[1], wd[3]);
            plswap(wd[4], wd[6]); plswap(wd[5], wd[7]);

            union { u32 u[4]; bf16x8 v; } p0, p1;
            p0.u[0] = wd[0]; p0.u[1] = wd[1]; p0.u[2] = wd[2]; p0.u[3] = wd[3];
            p1.u[0] = wd[4]; p1.u[1] = wd[5]; p1.u[2] = wd[6]; p1.u[3] = wd[7];

            __builtin_amdgcn_s_setprio(1);
            o_acc = __builtin_amdgcn_mfma_f32_32x32x16_bf16(p0.v, vf0, o_acc, 0, 0, 0);
            o_acc = __builtin_amdgcn_mfma_f32_32x32x16_bf16(p1.v, vf1, o_acc, 0, 0, 0);
            l_acc = __builtin_amdgcn_mfma_f32_32x32x16_bf16(p0.v, vone, l_acc, 0, 0, 0);
            l_acc = __builtin_amdgcn_mfma_f32_32x32x16_bf16(p1.v, vone, l_acc, 0, 0, 0);
            __builtin_amdgcn_s_setprio(0);

            if (jt < 3) s_cur = s_next;
        }
    }

    #pragma unroll
    for (int r = 0; r < 16; ++r) {
        int q_r = (r & 3) + 8 * (r >> 2) + 4 * half_id;
        size_t gq = (size_t)(b * Ndim + q0w + q_r);
        op[gq * INdim + head * 32 + col] = f2bf(o_acc[r]);
    }
    if (col < 16) {
        int r = col;
        int q_r = (r & 3) + 8 * (r >> 2) + 4 * half_id;
        lp[(size_t)(b * Ndim + q0w + q_r) * 8 + head] = l_acc[r];
    }
}

// ---------------------------------------------------------------------------
// launch
// ---------------------------------------------------------------------------
extern "C" void kernel_launch(void* const* d_in, const int* in_sizes, int n_in,
                              void* d_out, int out_size, void* d_ws, size_t ws_size,
                              hipStream_t stream) {
    const float* x     = (const float*)d_in[0];
    const float* g1    = (const float*)d_in[2];
    const float* b1    = (const float*)d_in[3];
    const float* Wqkv  = (const float*)d_in[4];
    const float* Wproj = (const float*)d_in[5];
    const float* bproj = (const float*)d_in[6];
    const float* g2    = (const float*)d_in[7];
    const float* b2    = (const float*)d_in[8];
    const float* W1    = (const float*)d_in[9];
    const float* bb1   = (const float*)d_in[10];
    const float* W2    = (const float*)d_in[11];
    const float* bb2   = (const float*)d_in[12];
    float* out = (float*)d_out;

    // workspace:
    //  [0,16M)  h fp32
    //  [16,24M) h_bf
    //  [24,48M) qkv_bf (dead after attn) -> xnew fp32 [24,40M)
    //  [48,64M) opart bf16 x2 (dead after PROJ) -> mid_bf [48,80M)
    //  [80,81M) lpart fp32 [2][Tdim*8]
    //  [81,89M) vT bf16
    //  [89,91M) weights bf16
    char* ws = (char*)d_ws;
    float* h      = (float*)(ws);
    short* h_bf   = (short*)(ws + (size_t)(16u << 20));
    short* qkv_bf = (short*)(ws + (size_t)(24u << 20));
    float* xnew   = (float*)(ws + (size_t)(24u << 20));
    short* opart  = (short*)(ws + (size_t)(48u << 20));
    short* mid_bf = (short*)(ws + (size_t)(48u << 20));
    float* lpart  = (float*)(ws + (size_t)(80u << 20));
    short* vT     = (short*)(ws + (size_t)(81u << 20));
    short* wqkv_b = (short*)(ws + (size_t)(89u << 20));
    short* wproj_b= (short*)(ws + (size_t)(89u << 20) + 768 * 1024);
    short* w1_b   = (short*)(ws + (size_t)(90u << 20));
    short* w2_b   = (short*)(ws + (size_t)(90u << 20) + 512 * 1024);

    // 0) all weights -> bf16 (single dispatch)
    cvt_all_kernel<<<(N4_QKV + N4_PROJ + N4_W1 + N4_W2 + 255) / 256, 256, 0, stream>>>(
        Wqkv, Wproj, W1, W2, wqkv_b, wproj_b, w1_b, w2_b);

    // 1) LN1: x -> h (fp32) + h_bf
    ln4_kernel<<<Tdim / 4, 256, 0, stream>>>(x, g1, b1, h, h_bf);
    // 2) qkv_bf = h_bf @ Wqkv^T (m97 128x128/BK64 gload_lds template)
    gemm128<EPI_QKV><<<dim3(768 / 128, Tdim / 128), 256, 0, stream>>>(
        h_bf, wqkv_b, qkv_bf, 768, 256, nullptr);
    // 2b) V transpose (once)
    vtrans_kernel<<<dim3(Bdim * Hdim, Ndim / 128), 256, 0, stream>>>(qkv_bf, vT);
    // 3) attention partials (j-split x2), XCD-locality 1D grid
    attn_mfma_kernel<<<2048, 256, 0, stream>>>(qkv_bf, vT, opart, lpart);
    // 4) xnew = ((O0+O1)/l) @ Wproj^T + bproj + h + x   (combine fused, reg-staged)
    gemm_mfma<EPI_PROJ, 64, true><<<dim3(256 / 64, Tdim / 64), 256, 0, stream>>>(
        opart, wproj_b, xnew, Tdim, 256, 256, bproj, h, x, lpart);
    // 5) LN2: xnew -> h_bf
    ln4_kernel<<<Tdim / 4, 256, 0, stream>>>(xnew, g2, b2, nullptr, h_bf);
    // 6) mid_bf = gelu(h2 @ W1^T + bb1)   (m97 template)
    gemm128<EPI_GELU><<<dim3(1024 / 128, Tdim / 128), 256, 0, stream>>>(
        h_bf, w1_b, mid_bf, 1024, 256, bb1);
    // 7) out = xnew + mid @ W2^T + bb2   (reg-staged, R9 config)
    gemm_mfma<EPI_RES, 64, false><<<dim3(256 / 64, Tdim / 64), 256, 0, stream>>>(
        mid_bf, w2_b, out, Tdim, 256, 1024, bb2, xnew, nullptr, nullptr);
}